// Round 22
// baseline (326.207 us; speedup 1.0000x reference)
//
#include <hip/hip_runtime.h>
#include <math.h>

typedef short  bf16x8 __attribute__((ext_vector_type(8)));
typedef float  f32x4  __attribute__((ext_vector_type(4)));
typedef float  f32x2  __attribute__((ext_vector_type(2)));

#define DIM   1024
#define RANK  256
#define NROWS 16
#define NT    512
#define NWAVE 8
#define TOTAL_ROWS 4096
#define OUT_HALF (TOTAL_ROWS*DIM)

// LDS byte layout (107 KB)
#define VS_OFF    0           // ushort[16][1024] swizzled: v / gamma / v'
#define H2_OFF    32768       // ushort[16][256] swizzled
#define STAGE_OFF 40960       // 8 slots x 8 KB staging ring (65536)
#define WS_OFF    106496      // float[16][8]
#define SG_OFF    107008      // float[16]
#define SMEM_BYTES 107072

static constexpr double XI  = 0.1786178958448091;
static constexpr double LAM = -0.2123418310626054;
static constexpr double CHI = -0.0662645826698185;

typedef __attribute__((address_space(1))) void as1_void;
typedef __attribute__((address_space(3))) void as3_void;

#define WAITV(n) asm volatile("s_waitcnt vmcnt(" #n ")" ::: "memory")

// phase barrier: LDS ops drained, global_load_lds stream stays in flight
__device__ __forceinline__ void bbar() {
    asm volatile("s_waitcnt lgkmcnt(0)" ::: "memory");
    __builtin_amdgcn_s_barrier();
}

__device__ __forceinline__ unsigned short f2bf(float f) {
    unsigned u = __builtin_bit_cast(unsigned, f);
    u += 0x7FFFu + ((u >> 16) & 1u);        // round-to-nearest-even
    return (unsigned short)(u >> 16);
}
__device__ __forceinline__ float bf2f(unsigned short b) {
    return __builtin_bit_cast(float, ((unsigned)b) << 16);
}

// swizzle: byte ^= (row&7)<<4
__device__ __forceinline__ int vs_addr(int m, int kb) {
    return VS_OFF + ((m * 2048 + kb) ^ ((m & 7) << 4));
}
__device__ __forceinline__ int h2_addr(int m, int kb) {
    return H2_OFF + ((m * 512 + kb) ^ ((m & 7) << 4));
}

// issue this wave's 1 frag (position w) of stream batch sb into the 8-slot ring.
// DEPTH-7 WAR invariant: called AFTER batch b's MFMA (+ sched_barrier pin),
// sb=b+7 writes slot (b-1)&7 — the slot read at batch b-1, whose ds_read was
// retired by the lgkm wait before batch b-1's MFMA (pinned last iteration).
// The sched_barrier stops hipcc sinking the register-only MFMA (and its lgkm
// wait) below the issue — the R17 failure (guide rule #18).
__device__ __forceinline__ void issue1(const char* pkb, char* smem_, int sb, int w, int lane) {
    char* dst = smem_ + STAGE_OFF + (sb & 7) * 8192 + w * 1024;
    const char* g = pkb + (size_t)(((unsigned)(sb * 8 + w)) << 10) + lane * 16;
    __builtin_amdgcn_global_load_lds((const as1_void*)g, (as3_void*)dst, 16, 0, 0);
}

// ---- prep: pack U,W into the bf16 consumption-order STREAM (128 batches x 8 KB).
// Batch b<64 (H): group=b>>5, ks=b&31; frag j = U-frag(kt=ks, nt=group*8+j).
// Batch 64+u (G): oct=u>>3, kk=u&7;  frag j = W-frag(kt=kk, nt=oct*8+j).
// B-frag 16x16x32: lane l holds B[k = kt*32 + (l>>4)*8 + jj][n = nt*16 + (l&15)]
__global__ __launch_bounds__(256)
void prep_pack(const float* __restrict__ U, const float* __restrict__ Wm,
               bf16x8* __restrict__ pk)
{
    const int tid  = blockIdx.x * 256 + threadIdx.x;   // 0..65535
    const int lane = tid & 63;
    const int frag = tid >> 6;                          // 0..1023
    const int b = frag >> 3, j = frag & 7;
    bf16x8 o;
    if (b < 64) {
        const int group = b >> 5, ks = b & 31;
        const int krow = ks * 32 + (lane >> 4) * 8;
        const int n    = (group * 8 + j) * 16 + (lane & 15);
        #pragma unroll
        for (int jj = 0; jj < 8; ++jj) o[jj] = (short)f2bf(U[(krow + jj) * RANK + n]);
    } else {
        const int u  = b - 64;
        const int oct = u >> 3, kk = u & 7;
        const int krow = kk * 32 + (lane >> 4) * 8;
        const int n    = (oct * 8 + j) * 16 + (lane & 15);
        #pragma unroll
        for (int jj = 0; jj < 8; ++jj) o[jj] = (short)f2bf(Wm[(krow + jj) * DIM + n]);
    }
    pk[frag * 64 + lane] = o;
}

__global__ __launch_bounds__(NT)
void omelyan_mfma(const float* __restrict__ x_in,
                  const float* __restrict__ v_in,
                  const float* __restrict__ force,
                  const float* __restrict__ Vw,
                  const int* __restrict__ steps_p,
                  const bf16x8* __restrict__ pk,
                  float* __restrict__ out)
{
    extern __shared__ char smem[];
    float* wsums = (float*)(smem + WS_OFF);
    float* sings = (float*)(smem + SG_OFF);
    const char* pkb = (const char*)pk;

    const int t    = threadIdx.x;        // 0..511
    const int lane = t & 63;
    const int w    = t >> 6;             // 0..7
    const int row0 = blockIdx.x * NROWS;
    const int nsteps = steps_p[0];

    const float dt = 0.01f;

    // per-thread state: elements (m, d = 2t+j), j=0,1
    float xr[NROWS][2], vr[NROWS][2];
    const f32x2 vw = *(const f32x2*)&Vw[2 * t];

    #pragma unroll
    for (int m = 0; m < NROWS; ++m) {
        const int base = (row0 + m) * DIM + 2 * t;
        const f32x2 xv = *(const f32x2*)&x_in[base];
        const f32x2 vv = *(const f32x2*)&v_in[base];
        xr[m][0] = xv[0]; xr[m][1] = xv[1];
        vr[m][0] = vv[0]; vr[m][1] = vv[1];
        const unsigned p = (unsigned)f2bf(vv[0]) | ((unsigned)f2bf(vv[1]) << 16);
        *(unsigned*)(smem + vs_addr(m, 4 * t)) = p;
    }
    __syncthreads();    // clean vmcnt base

    // prime the stream: batches 0..6 (depth 7 -> 7 loads/wave in flight)
    #pragma unroll
    for (int b = 0; b < 7; ++b) issue1(pkb, smem, b, w, lane);

    #pragma unroll 1
    for (int step = 0; step < nsteps; ++step) {
        #pragma unroll 1
        for (int sub = 0; sub < 4; ++sub) {
            const float cdt = dt * (sub == 0 ? (float)XI :
                                    sub == 1 ? (float)CHI :
                                    sub == 2 ? (float)(1.0 - 2.0 * (CHI + XI)) :
                                               (float)CHI);
            const float ddt = dt * ((sub == 0 || sub == 3)
                                    ? (float)((1.0 - 2.0 * LAM) * 0.5)
                                    : (float)LAM);

            // ---- drift x + r2 reduce -> wsums ----
            #pragma unroll
            for (int m = 0; m < NROWS; ++m) {
                float s = 0.f;
                #pragma unroll
                for (int j = 0; j < 2; ++j) {
                    xr[m][j] = fmaf(cdt, vr[m][j], xr[m][j]);
                    s = fmaf(xr[m][j], xr[m][j], s);
                }
                #pragma unroll
                for (int off = 32; off >= 1; off >>= 1) s += __shfl_xor(s, off, 64);
                if (lane == 0) wsums[m * NWAVE + w] = s;
            }
            bbar();                         // b_A: prior kick's vs + wsums visible
            if (t < NROWS) {
                float r2 = 0.f;
                #pragma unroll
                for (int q = 0; q < NWAVE; ++q) r2 += wsums[t * NWAVE + q];
                sings[t] = 1.f + exp2f(-r2 * 1.4426950408889634f);
            }

            // ---- H: 2 groups x 32 ks (wave w owns nt = group*8 + w) ----
            #pragma unroll 1
            for (int group = 0; group < 2; ++group) {
                f32x4 hacc = {0.f, 0.f, 0.f, 0.f};
                #pragma unroll 2
                for (int ks = 0; ks < 32; ++ks) {
                    const int b = group * 32 + ks;
                    WAITV(6);                // own load for batch b retired
                    const bf16x8 a = *(const bf16x8*)(smem + vs_addr(lane & 15, ks * 64 + (lane >> 4) * 16));
                    const bf16x8 f = *(const bf16x8*)(smem + STAGE_OFF + (b & 7) * 8192 + w * 1024 + lane * 16);
                    hacc = __builtin_amdgcn_mfma_f32_16x16x32_bf16(a, f, hacc, 0, 0, 0);
                    __builtin_amdgcn_sched_barrier(0);   // pin MFMA+lgkm above issue
                    issue1(pkb, smem, (b + 7) & 127, w, lane);   // writes slot (b-1)&7
                }
                // h2 = h*h (bf16, swizzled); D: col=lane&15, row=(lane>>4)*4+r
                #pragma unroll
                for (int r = 0; r < 4; ++r) {
                    const int m = (lane >> 4) * 4 + r;
                    const int n = (group * 8 + w) * 16 + (lane & 15);
                    *(unsigned short*)(smem + h2_addr(m, 2 * n)) = f2bf(hacc[r] * hacc[r]);
                }
            }
            bbar();                         // b_B: h2 visible

            // ---- G: 8 octs x 8 kk (wave w owns nt = oct*8 + w) ----
            #pragma unroll 1
            for (int oct = 0; oct < 8; ++oct) {
                f32x4 g = {0.f, 0.f, 0.f, 0.f};
                #pragma unroll 2
                for (int kk = 0; kk < 8; ++kk) {
                    const int b = 64 + oct * 8 + kk;
                    WAITV(6);
                    const bf16x8 a = *(const bf16x8*)(smem + h2_addr(lane & 15, kk * 64 + (lane >> 4) * 16));
                    const bf16x8 f = *(const bf16x8*)(smem + STAGE_OFF + (b & 7) * 8192 + w * 1024 + lane * 16);
                    g = __builtin_amdgcn_mfma_f32_16x16x32_bf16(a, f, g, 0, 0, 0);
                    __builtin_amdgcn_sched_barrier(0);
                    issue1(pkb, smem, (b + 7) & 127, w, lane);  // wraps to next accel's 0..6
                }
                // gamma (bf16) into dead vs cells, nt = oct*8 + w (wave-exclusive)
                #pragma unroll
                for (int r = 0; r < 4; ++r) {
                    const int m = (lane >> 4) * 4 + r;
                    const int n = (oct * 8 + w) * 16 + (lane & 15);
                    *(unsigned short*)(smem + vs_addr(m, 2 * n)) = f2bf(g[r]);
                }
            }
            bbar();                                     // b_C: gamma visible

            // ---- kick: read gamma from vs cells, write v' back to same cells ----
            #pragma unroll
            for (int m = 0; m < NROWS; ++m) {
                const f32x2 fm = *(const f32x2*)&force[(row0 + m) * DIM + 2 * t];
                const unsigned gu = *(const unsigned*)(smem + vs_addr(m, 4 * t));
                const float gL = bf2f((unsigned short)(gu & 0xFFFFu));
                const float gH = bf2f((unsigned short)(gu >> 16));
                const float sing = sings[m];
                unsigned pp = 0;
                #pragma unroll
                for (int j = 0; j < 2; ++j) {
                    const float g  = j ? gH : gL;
                    const float z  = xr[m][j] * vw[j];
                    const float e  = exp2f(z * 2.885390081777927f);   // e^(2z)
                    const float th = 1.f - 2.f / (e + 1.f);           // tanh(z)
                    const float gate = fmaf(0.1f, th, 1.f);
                    const float a = fm[j] - g * gate * sing;
                    vr[m][j] = fmaf(ddt, a, vr[m][j]);
                    pp |= ((unsigned)f2bf(vr[m][j])) << (16 * j);
                }
                *(unsigned*)(smem + vs_addr(m, 4 * t)) = pp;   // same-thread RMW
            }
            // next accel's b_A covers these vs writes
        } // sub

        // final drift: x += C5*dt*v
        const float c5dt = dt * (float)XI;
        #pragma unroll
        for (int m = 0; m < NROWS; ++m)
            #pragma unroll
            for (int j = 0; j < 2; ++j)
                xr[m][j] = fmaf(c5dt, vr[m][j], xr[m][j]);
    } // step

    __syncthreads();    // drain dangling prefetches before store

    // ---- store (x, v) ----
    #pragma unroll
    for (int m = 0; m < NROWS; ++m) {
        const int base = (row0 + m) * DIM + 2 * t;
        f32x2 xo, vo;
        xo[0] = xr[m][0]; xo[1] = xr[m][1];
        vo[0] = vr[m][0]; vo[1] = vr[m][1];
        *(f32x2*)&out[base] = xo;
        *(f32x2*)&out[OUT_HALF + base] = vo;
    }
}

extern "C" void kernel_launch(void* const* d_in, const int* in_sizes, int n_in,
                              void* d_out, int out_size, void* d_ws, size_t ws_size,
                              hipStream_t stream) {
    const float* x_in  = (const float*)d_in[0];
    const float* v_in  = (const float*)d_in[1];
    const float* force = (const float*)d_in[2];
    const float* Umat  = (const float*)d_in[3];
    const float* Wmat  = (const float*)d_in[4];
    const float* Vw    = (const float*)d_in[5];
    const int*   steps = (const int*)d_in[6];
    float* out = (float*)d_out;
    bf16x8* pk = (bf16x8*)d_ws;   // 1 MiB stream

    (void)hipFuncSetAttribute((const void*)omelyan_mfma,
                              hipFuncAttributeMaxDynamicSharedMemorySize,
                              SMEM_BYTES);

    prep_pack<<<dim3(256), dim3(256), 0, stream>>>(Umat, Wmat, pk);
    omelyan_mfma<<<dim3(TOTAL_ROWS / NROWS), dim3(NT), SMEM_BYTES, stream>>>(
        x_in, v_in, force, Vw, steps, pk, out);
}

// Round 23
// 296.482 us; speedup vs baseline: 1.1003x; 1.1003x over previous
//
#include <hip/hip_runtime.h>
#include <math.h>

typedef short  bf16x8 __attribute__((ext_vector_type(8)));
typedef float  f32x4  __attribute__((ext_vector_type(4)));
typedef float  f32x2  __attribute__((ext_vector_type(2)));

#define DIM   1024
#define RANK  256
#define NROWS 16
#define NT    512
#define NWAVE 8
#define TOTAL_ROWS 4096
#define OUT_HALF (TOTAL_ROWS*DIM)

// LDS byte layout
#define VS_OFF    0           // ushort[16][1024] swizzled: v (H input) / gamma (G out) / v' (kick)
#define H2_OFF    32768       // ushort[16][256] swizzled
#define STAGE_OFF 40960       // 4 slots x 16 KB staging ring (65536)
#define SLOTS     4
#define WS_OFF    106496      // float[16][8]
#define SG_OFF    107008      // float[16]
#define SMEM_BYTES 107072

static constexpr double XI  = 0.1786178958448091;
static constexpr double LAM = -0.2123418310626054;
static constexpr double CHI = -0.0662645826698185;

typedef __attribute__((address_space(1))) void as1_void;
typedef __attribute__((address_space(3))) void as3_void;

#define WAITV(n) asm volatile("s_waitcnt vmcnt(" #n ")" ::: "memory")
// counted WAR guard: wait until at most n lgkm ops outstanding. Placed right
// after this iteration's n ds_reads, it retires all OLDER lds ops (in-order
// retirement) — in particular the previous batch's reads of the slot the
// following issue2 rewrites. ~0 stall (those reads are a full iteration old).
// Unlike sched_barrier(0) [R20/R22], this does NOT block the compiler from
// software-pipelining iterations; unlike relying on the MFMA's implicit lgkm
// wait [R17 bug], it is immune to MFMA sinking (guide rule #18): once a
// ds_read RETIRES the data is in VGPRs, and MFMA placement is irrelevant.
#define WAITL(n) asm volatile("s_waitcnt lgkmcnt(" #n ")" ::: "memory")

// phase barrier: LDS ops drained, global_load_lds stream stays in flight
__device__ __forceinline__ void bbar() {
    asm volatile("s_waitcnt lgkmcnt(0)" ::: "memory");
    __builtin_amdgcn_s_barrier();
}

__device__ __forceinline__ unsigned short f2bf(float f) {
    unsigned u = __builtin_bit_cast(unsigned, f);
    u += 0x7FFFu + ((u >> 16) & 1u);        // round-to-nearest-even
    return (unsigned short)(u >> 16);
}
__device__ __forceinline__ float bf2f(unsigned short b) {
    return __builtin_bit_cast(float, ((unsigned)b) << 16);
}

// swizzle: byte ^= (row&7)<<4
__device__ __forceinline__ int vs_addr(int m, int kb) {
    return VS_OFF + ((m * 2048 + kb) ^ ((m & 7) << 4));
}
__device__ __forceinline__ int h2_addr(int m, int kb) {
    return H2_OFF + ((m * 512 + kb) ^ ((m & 7) << 4));
}

// issue this wave's 2 frags (positions 2w, 2w+1) of stream batch sb into the ring.
// Wave-private staging. DEPTH-3 WAR invariant: called after the WAITL guard,
// sb=b+3 writes slot (b-1)&3, whose ds_reads are provably retired.
__device__ __forceinline__ void issue2(const char* pkb, char* smem_, int sb, int w, int lane) {
    char* dst = smem_ + STAGE_OFF + (sb & (SLOTS - 1)) * 16384 + (2 * w) * 1024;
    const char* g = pkb + (size_t)(((unsigned)(sb * 16 + 2 * w)) << 10) + lane * 16;
    __builtin_amdgcn_global_load_lds((const as1_void*)g,          (as3_void*)dst,          16, 0, 0);
    __builtin_amdgcn_global_load_lds((const as1_void*)(g + 1024), (as3_void*)(dst + 1024), 16, 0, 0);
}

// ---- prep: pack U,W into the bf16 consumption-order STREAM (64 batches x 16 KB).
// Batch b<32 (H, ks=b): frag j = U-fragment(kt=b, nt=j).
// Batch 32+idx (G): region=idx>>4 (pass A/B), ga=idx&15, kk=ga>>1, p=ga&1;
//   frag j (w'=j>>1, i=j&1) = W-fragment(kt=kk, nt = 8w' + 4*region + 2p + i).
// B-frag 16x16x32: lane l holds B[k = kt*32 + (l>>4)*8 + jj][n = nt*16 + (l&15)]
__global__ __launch_bounds__(256)
void prep_pack(const float* __restrict__ U, const float* __restrict__ Wm,
               bf16x8* __restrict__ pk)
{
    const int tid  = blockIdx.x * 256 + threadIdx.x;   // 0..65535
    const int lane = tid & 63;
    const int frag = tid >> 6;                          // 0..1023
    bf16x8 o;
    if (frag < 512) {
        const int kt = frag >> 4, nt = frag & 15;
        const int krow = kt * 32 + (lane >> 4) * 8;
        const int n    = nt * 16 + (lane & 15);
        #pragma unroll
        for (int j = 0; j < 8; ++j) o[j] = (short)f2bf(U[(krow + j) * RANK + n]);
    } else {
        const int idx = frag - 512;                     // 0..511
        const int b   = idx >> 4;                       // 0..31
        const int j   = idx & 15;
        const int region = b >> 4;                      // 0 = pass A, 1 = pass B
        const int ga  = b & 15;
        const int kk  = ga >> 1, p = ga & 1;
        const int wv  = j >> 1, i = j & 1;
        const int nt  = wv * 8 + region * 4 + p * 2 + i;
        const int krow = kk * 32 + (lane >> 4) * 8;
        const int n    = nt * 16 + (lane & 15);
        #pragma unroll
        for (int jj = 0; jj < 8; ++jj) o[jj] = (short)f2bf(Wm[(krow + jj) * DIM + n]);
    }
    pk[frag * 64 + lane] = o;
}

__global__ __launch_bounds__(NT)
void omelyan_mfma(const float* __restrict__ x_in,
                  const float* __restrict__ v_in,
                  const float* __restrict__ force,
                  const float* __restrict__ Vw,
                  const int* __restrict__ steps_p,
                  const bf16x8* __restrict__ pk,
                  float* __restrict__ out)
{
    extern __shared__ char smem[];
    float* wsums = (float*)(smem + WS_OFF);
    float* sings = (float*)(smem + SG_OFF);
    const char* pkb = (const char*)pk;

    const int t    = threadIdx.x;        // 0..511
    const int lane = t & 63;
    const int w    = t >> 6;             // 0..7
    const int row0 = blockIdx.x * NROWS;
    const int nsteps = steps_p[0];

    const float dt = 0.01f;

    // per-thread state: elements (m, d = 2t+j), j=0,1
    float xr[NROWS][2], vr[NROWS][2];
    const f32x2 vw = *(const f32x2*)&Vw[2 * t];

    #pragma unroll
    for (int m = 0; m < NROWS; ++m) {
        const int base = (row0 + m) * DIM + 2 * t;
        const f32x2 xv = *(const f32x2*)&x_in[base];
        const f32x2 vv = *(const f32x2*)&v_in[base];
        xr[m][0] = xv[0]; xr[m][1] = xv[1];
        vr[m][0] = vv[0]; vr[m][1] = vv[1];
        const unsigned p = (unsigned)f2bf(vv[0]) | ((unsigned)f2bf(vv[1]) << 16);
        *(unsigned*)(smem + vs_addr(m, 4 * t)) = p;
    }
    __syncthreads();    // clean vmcnt base

    // prime the stream: batches 0..2 (depth 3 -> 6 loads/wave in flight)
    issue2(pkb, smem, 0, w, lane);
    issue2(pkb, smem, 1, w, lane);
    issue2(pkb, smem, 2, w, lane);

    #pragma unroll 1
    for (int step = 0; step < nsteps; ++step) {
        #pragma unroll 1
        for (int sub = 0; sub < 4; ++sub) {
            const float cdt = dt * (sub == 0 ? (float)XI :
                                    sub == 1 ? (float)CHI :
                                    sub == 2 ? (float)(1.0 - 2.0 * (CHI + XI)) :
                                               (float)CHI);
            const float ddt = dt * ((sub == 0 || sub == 3)
                                    ? (float)((1.0 - 2.0 * LAM) * 0.5)
                                    : (float)LAM);

            // ---- drift x + r2 reduce -> wsums ----
            #pragma unroll
            for (int m = 0; m < NROWS; ++m) {
                float s = 0.f;
                #pragma unroll
                for (int j = 0; j < 2; ++j) {
                    xr[m][j] = fmaf(cdt, vr[m][j], xr[m][j]);
                    s = fmaf(xr[m][j], xr[m][j], s);
                }
                #pragma unroll
                for (int off = 32; off >= 1; off >>= 1) s += __shfl_xor(s, off, 64);
                if (lane == 0) wsums[m * NWAVE + w] = s;
            }
            bbar();                         // b_A: prior kick's vs + wsums visible
            if (t < NROWS) {
                float r2 = 0.f;
                #pragma unroll
                for (int q = 0; q < NWAVE; ++q) r2 += wsums[t * NWAVE + q];
                sings[t] = 1.f + exp2f(-r2 * 1.4426950408889634f);
            }

            // ---- H: batches 0..31 (wave consumes nt 2w, 2w+1) ----
            f32x4 h0 = {0.f,0.f,0.f,0.f}, h1 = {0.f,0.f,0.f,0.f};
            #pragma unroll 2
            for (int ks = 0; ks < 32; ++ks) {
                WAITV(4);                    // own 2 loads for batch ks retired
                const bf16x8 a  = *(const bf16x8*)(smem + vs_addr(lane & 15, ks * 64 + (lane >> 4) * 16));
                const char* sp = smem + STAGE_OFF + ((ks & 3) * 16384) + (2 * w) * 1024 + lane * 16;
                const bf16x8 f0 = *(const bf16x8*)sp;
                const bf16x8 f1 = *(const bf16x8*)(sp + 1024);
                WAITL(3);                    // batch ks-1's reads retired -> slot free
                issue2(pkb, smem, (ks + 3) & 63, w, lane);   // writes slot (ks-1)&3
                h0 = __builtin_amdgcn_mfma_f32_16x16x32_bf16(a, f0, h0, 0, 0, 0);
                h1 = __builtin_amdgcn_mfma_f32_16x16x32_bf16(a, f1, h1, 0, 0, 0);
            }
            // h2 = h*h (bf16, swizzled); D: col=lane&15, row=(lane>>4)*4+r
            #pragma unroll
            for (int r = 0; r < 4; ++r) {
                const int m = (lane >> 4) * 4 + r;
                const int c = lane & 15;
                *(unsigned short*)(smem + h2_addr(m, 2 * ((2 * w + 0) * 16 + c))) = f2bf(h0[r] * h0[r]);
                *(unsigned short*)(smem + h2_addr(m, 2 * ((2 * w + 1) * 16 + c))) = f2bf(h1[r] * h1[r]);
            }
            bbar();                         // b_B: h2 visible

            // ---- G pass A: batches 32..47 (nt 8w..8w+3), flattened u-loop ----
            {
                f32x4 g0 = {0.f,0.f,0.f,0.f}, g1 = {0.f,0.f,0.f,0.f};
                f32x4 g2 = {0.f,0.f,0.f,0.f}, g3 = {0.f,0.f,0.f,0.f};
                #pragma unroll 2
                for (int u = 0; u < 16; ++u) {
                    const int kk = u >> 1, p = u & 1;   // p static at even unroll boundary
                    const int b = 32 + u;
                    WAITV(4);
                    const bf16x8 a = *(const bf16x8*)(smem + h2_addr(lane & 15, kk * 64 + (lane >> 4) * 16));
                    const char* sp = smem + STAGE_OFF + ((b & 3) * 16384) + (2 * w) * 1024 + lane * 16;
                    const bf16x8 f0 = *(const bf16x8*)sp;
                    const bf16x8 f1 = *(const bf16x8*)(sp + 1024);
                    WAITL(3);
                    issue2(pkb, smem, (b + 3) & 63, w, lane);
                    if (p == 0) {
                        g0 = __builtin_amdgcn_mfma_f32_16x16x32_bf16(a, f0, g0, 0, 0, 0);
                        g1 = __builtin_amdgcn_mfma_f32_16x16x32_bf16(a, f1, g1, 0, 0, 0);
                    } else {
                        g2 = __builtin_amdgcn_mfma_f32_16x16x32_bf16(a, f0, g2, 0, 0, 0);
                        g3 = __builtin_amdgcn_mfma_f32_16x16x32_bf16(a, f1, g3, 0, 0, 0);
                    }
                }
                // gamma (bf16) into the dead vs region (wave-exclusive cols)
                #pragma unroll
                for (int r = 0; r < 4; ++r) {
                    const int m = (lane >> 4) * 4 + r;
                    const int c = lane & 15;
                    *(unsigned short*)(smem + vs_addr(m, 2 * ((8 * w + 0) * 16 + c))) = f2bf(g0[r]);
                    *(unsigned short*)(smem + vs_addr(m, 2 * ((8 * w + 1) * 16 + c))) = f2bf(g1[r]);
                    *(unsigned short*)(smem + vs_addr(m, 2 * ((8 * w + 2) * 16 + c))) = f2bf(g2[r]);
                    *(unsigned short*)(smem + vs_addr(m, 2 * ((8 * w + 3) * 16 + c))) = f2bf(g3[r]);
                }
            }

            // ---- G pass B: batches 48..63 (nt 8w+4..8w+7) ----
            {
                f32x4 g0 = {0.f,0.f,0.f,0.f}, g1 = {0.f,0.f,0.f,0.f};
                f32x4 g2 = {0.f,0.f,0.f,0.f}, g3 = {0.f,0.f,0.f,0.f};
                #pragma unroll 2
                for (int u = 0; u < 16; ++u) {
                    const int kk = u >> 1, p = u & 1;
                    const int b = 48 + u;
                    WAITV(4);
                    const bf16x8 a = *(const bf16x8*)(smem + h2_addr(lane & 15, kk * 64 + (lane >> 4) * 16));
                    const char* sp = smem + STAGE_OFF + ((b & 3) * 16384) + (2 * w) * 1024 + lane * 16;
                    const bf16x8 f0 = *(const bf16x8*)sp;
                    const bf16x8 f1 = *(const bf16x8*)(sp + 1024);
                    WAITL(3);
                    issue2(pkb, smem, (b + 3) & 63, w, lane);  // wraps to next accel's 0..2
                    if (p == 0) {
                        g0 = __builtin_amdgcn_mfma_f32_16x16x32_bf16(a, f0, g0, 0, 0, 0);
                        g1 = __builtin_amdgcn_mfma_f32_16x16x32_bf16(a, f1, g1, 0, 0, 0);
                    } else {
                        g2 = __builtin_amdgcn_mfma_f32_16x16x32_bf16(a, f0, g2, 0, 0, 0);
                        g3 = __builtin_amdgcn_mfma_f32_16x16x32_bf16(a, f1, g3, 0, 0, 0);
                    }
                }
                #pragma unroll
                for (int r = 0; r < 4; ++r) {
                    const int m = (lane >> 4) * 4 + r;
                    const int c = lane & 15;
                    *(unsigned short*)(smem + vs_addr(m, 2 * ((8 * w + 4) * 16 + c))) = f2bf(g0[r]);
                    *(unsigned short*)(smem + vs_addr(m, 2 * ((8 * w + 5) * 16 + c))) = f2bf(g1[r]);
                    *(unsigned short*)(smem + vs_addr(m, 2 * ((8 * w + 6) * 16 + c))) = f2bf(g2[r]);
                    *(unsigned short*)(smem + vs_addr(m, 2 * ((8 * w + 7) * 16 + c))) = f2bf(g3[r]);
                }
            }
            bbar();                                     // b_C: gamma visible

            // ---- kick: read gamma from vs cells, write v' back to same cells ----
            #pragma unroll
            for (int m = 0; m < NROWS; ++m) {
                const f32x2 fm = *(const f32x2*)&force[(row0 + m) * DIM + 2 * t];
                const unsigned gu = *(const unsigned*)(smem + vs_addr(m, 4 * t));
                const float gL = bf2f((unsigned short)(gu & 0xFFFFu));
                const float gH = bf2f((unsigned short)(gu >> 16));
                const float sing = sings[m];
                unsigned pp = 0;
                #pragma unroll
                for (int j = 0; j < 2; ++j) {
                    const float g  = j ? gH : gL;
                    const float z  = xr[m][j] * vw[j];
                    const float e  = exp2f(z * 2.885390081777927f);   // e^(2z)
                    const float th = 1.f - 2.f / (e + 1.f);           // tanh(z)
                    const float gate = fmaf(0.1f, th, 1.f);
                    const float a = fm[j] - g * gate * sing;
                    vr[m][j] = fmaf(ddt, a, vr[m][j]);
                    pp |= ((unsigned)f2bf(vr[m][j])) << (16 * j);
                }
                *(unsigned*)(smem + vs_addr(m, 4 * t)) = pp;   // same-thread RMW
            }
            // next accel's b_A covers these vs writes
        } // sub

        // final drift: x += C5*dt*v
        const float c5dt = dt * (float)XI;
        #pragma unroll
        for (int m = 0; m < NROWS; ++m)
            #pragma unroll
            for (int j = 0; j < 2; ++j)
                xr[m][j] = fmaf(c5dt, vr[m][j], xr[m][j]);
    } // step

    __syncthreads();    // drain dangling prefetches before store

    // ---- store (x, v) ----
    #pragma unroll
    for (int m = 0; m < NROWS; ++m) {
        const int base = (row0 + m) * DIM + 2 * t;
        f32x2 xo, vo;
        xo[0] = xr[m][0]; xo[1] = xr[m][1];
        vo[0] = vr[m][0]; vo[1] = vr[m][1];
        *(f32x2*)&out[base] = xo;
        *(f32x2*)&out[OUT_HALF + base] = vo;
    }
}

extern "C" void kernel_launch(void* const* d_in, const int* in_sizes, int n_in,
                              void* d_out, int out_size, void* d_ws, size_t ws_size,
                              hipStream_t stream) {
    const float* x_in  = (const float*)d_in[0];
    const float* v_in  = (const float*)d_in[1];
    const float* force = (const float*)d_in[2];
    const float* Umat  = (const float*)d_in[3];
    const float* Wmat  = (const float*)d_in[4];
    const float* Vw    = (const float*)d_in[5];
    const int*   steps = (const int*)d_in[6];
    float* out = (float*)d_out;
    bf16x8* pk = (bf16x8*)d_ws;   // 1 MiB stream

    (void)hipFuncSetAttribute((const void*)omelyan_mfma,
                              hipFuncAttributeMaxDynamicSharedMemorySize,
                              SMEM_BYTES);

    prep_pack<<<dim3(256), dim3(256), 0, stream>>>(Umat, Wmat, pk);
    omelyan_mfma<<<dim3(TOTAL_ROWS / NROWS), dim3(NT), SMEM_BYTES, stream>>>(
        x_in, v_in, force, Vw, steps, pk, out);
}

// Round 24
// 275.194 us; speedup vs baseline: 1.1854x; 1.0774x over previous
//
#include <hip/hip_runtime.h>
#include <math.h>

typedef short  bf16x8 __attribute__((ext_vector_type(8)));
typedef float  f32x4  __attribute__((ext_vector_type(4)));
typedef float  f32x2  __attribute__((ext_vector_type(2)));

#define DIM   1024
#define RANK  256
#define NROWS 16
#define NT    512
#define NWAVE 8
#define TOTAL_ROWS 4096
#define OUT_HALF (TOTAL_ROWS*DIM)

// LDS byte layout (107 KB) — NO staging ring: B-frags stream global->VGPR.
#define VS_OFF    0           // ushort[16][1024] swizzled: v / gamma / v'
#define H2_OFF    32768       // ushort[16][256] swizzled
#define XS_OFF    40960       // float[16][1024] thread-private x state (65536)
#define WS_OFF    106496      // float[16][8]
#define SG_OFF    107008      // float[16]
#define SMEM_BYTES 107072

static constexpr double XI  = 0.1786178958448091;
static constexpr double LAM = -0.2123418310626054;
static constexpr double CHI = -0.0662645826698185;

__device__ __forceinline__ unsigned short f2bf(float f) {
    unsigned u = __builtin_bit_cast(unsigned, f);
    u += 0x7FFFu + ((u >> 16) & 1u);        // round-to-nearest-even
    return (unsigned short)(u >> 16);
}
__device__ __forceinline__ float bf2f(unsigned short b) {
    return __builtin_bit_cast(float, ((unsigned)b) << 16);
}

// swizzle: byte ^= (row&7)<<4
__device__ __forceinline__ int vs_addr(int m, int kb) {
    return VS_OFF + ((m * 2048 + kb) ^ ((m & 7) << 4));
}
__device__ __forceinline__ int h2_addr(int m, int kb) {
    return H2_OFF + ((m * 512 + kb) ^ ((m & 7) << 4));
}

// ---- prep: pack U,W (fp32) into bf16 MFMA B-fragment order (simple layout).
// U slot = kt*16+nt (kt<32,nt<16); W slot = 512 + kt*64+nt (kt<8,nt<64)
// B-frag 16x16x32: lane l holds B[k = kt*32 + (l>>4)*8 + j][n = nt*16 + (l&15)]
__global__ __launch_bounds__(256)
void prep_pack(const float* __restrict__ U, const float* __restrict__ Wm,
               bf16x8* __restrict__ pk)
{
    const int tid  = blockIdx.x * 256 + threadIdx.x;   // 0..65535
    const int lane = tid & 63;
    const int frag = tid >> 6;                          // 0..1023
    bf16x8 o;
    if (frag < 512) {
        const int kt = frag >> 4, nt = frag & 15;
        const int krow = kt * 32 + (lane >> 4) * 8;
        const int n    = nt * 16 + (lane & 15);
        #pragma unroll
        for (int j = 0; j < 8; ++j) o[j] = (short)f2bf(U[(krow + j) * RANK + n]);
    } else {
        const int f = frag - 512;
        const int kt = f >> 6, nt = f & 63;
        const int krow = kt * 32 + (lane >> 4) * 8;
        const int n    = nt * 16 + (lane & 15);
        #pragma unroll
        for (int j = 0; j < 8; ++j) o[j] = (short)f2bf(Wm[(krow + j) * DIM + n]);
    }
    pk[frag * 64 + lane] = o;
}

__global__ __launch_bounds__(NT)
void omelyan_mfma(const float* __restrict__ x_in,
                  const float* __restrict__ v_in,
                  const float* __restrict__ force,
                  const float* __restrict__ Vw,
                  const int* __restrict__ steps_p,
                  const bf16x8* __restrict__ pk,
                  float* __restrict__ out)
{
    extern __shared__ char smem[];
    float* wsums = (float*)(smem + WS_OFF);
    float* sings = (float*)(smem + SG_OFF);
    float* xsp   = (float*)(smem + XS_OFF);   // [16][1024] f32, thread-private

    const int t    = threadIdx.x;        // 0..511
    const int lane = t & 63;
    const int w    = t >> 6;             // 0..7
    const int row0 = blockIdx.x * NROWS;
    const int nsteps = steps_p[0];

    const float dt = 0.01f;

    // per-thread register state: ONLY v (elements d = 2t+j) + vw.
    // x lives in LDS (thread-private slots) to keep VGPR demand ~105 < 128.
    float vr[NROWS][2];
    const f32x2 vw = *(const f32x2*)&Vw[2 * t];

    #pragma unroll
    for (int m = 0; m < NROWS; ++m) {
        const int base = (row0 + m) * DIM + 2 * t;
        const f32x2 xv = *(const f32x2*)&x_in[base];
        const f32x2 vv = *(const f32x2*)&v_in[base];
        vr[m][0] = vv[0]; vr[m][1] = vv[1];
        *(f32x2*)&xsp[m * 1024 + 2 * t] = xv;
        const unsigned p = (unsigned)f2bf(vv[0]) | ((unsigned)f2bf(vv[1]) << 16);
        *(unsigned*)(smem + vs_addr(m, 4 * t)) = p;
    }
    __syncthreads();

    #pragma unroll 1
    for (int step = 0; step < nsteps; ++step) {
        #pragma unroll 1
        for (int sub = 0; sub < 4; ++sub) {
            const float cdt = dt * (sub == 0 ? (float)XI :
                                    sub == 1 ? (float)CHI :
                                    sub == 2 ? (float)(1.0 - 2.0 * (CHI + XI)) :
                                               (float)CHI);
            const float ddt = dt * ((sub == 0 || sub == 3)
                                    ? (float)((1.0 - 2.0 * LAM) * 0.5)
                                    : (float)LAM);

            // ---- drift x (LDS RMW, thread-private) + r2 reduce -> wsums ----
            #pragma unroll
            for (int m = 0; m < NROWS; ++m) {
                f32x2 x2 = *(f32x2*)&xsp[m * 1024 + 2 * t];
                x2[0] = fmaf(cdt, vr[m][0], x2[0]);
                x2[1] = fmaf(cdt, vr[m][1], x2[1]);
                *(f32x2*)&xsp[m * 1024 + 2 * t] = x2;
                float s = fmaf(x2[0], x2[0], x2[1] * x2[1]);
                #pragma unroll
                for (int off = 32; off >= 1; off >>= 1) s += __shfl_xor(s, off, 64);
                if (lane == 0) wsums[m * NWAVE + w] = s;
            }
            __syncthreads();                 // b_A: vs(v') + wsums visible
            if (t < NROWS) {
                float r2 = 0.f;
                #pragma unroll
                for (int q = 0; q < NWAVE; ++q) r2 += wsums[t * NWAVE + q];
                sings[t] = 1.f + exp2f(-r2 * 1.4426950408889634f);
            }

            // ---- H: h = v @ U; wave owns nt {2w, 2w+1}; B-frags global->VGPR ----
            {
                f32x4 h0 = {0.f,0.f,0.f,0.f}, h1 = {0.f,0.f,0.f,0.f};
                bf16x8 bb[4][2];             // ring-4, all indices compile-time
                #pragma unroll
                for (int d = 0; d < 4; ++d) {
                    bb[d][0] = pk[(d * 16 + 2 * w + 0) * 64 + lane];
                    bb[d][1] = pk[(d * 16 + 2 * w + 1) * 64 + lane];
                }
                #pragma unroll 4
                for (int ks = 0; ks < 32; ++ks) {
                    const bf16x8 a = *(const bf16x8*)(smem + vs_addr(lane & 15, ks * 64 + (lane >> 4) * 16));
                    h0 = __builtin_amdgcn_mfma_f32_16x16x32_bf16(a, bb[ks & 3][0], h0, 0, 0, 0);
                    h1 = __builtin_amdgcn_mfma_f32_16x16x32_bf16(a, bb[ks & 3][1], h1, 0, 0, 0);
                    if (ks + 4 < 32) {
                        bb[ks & 3][0] = pk[((ks + 4) * 16 + 2 * w + 0) * 64 + lane];
                        bb[ks & 3][1] = pk[((ks + 4) * 16 + 2 * w + 1) * 64 + lane];
                    }
                }
                // h2 = h*h (bf16, swizzled); D: col=lane&15, row=(lane>>4)*4+r
                #pragma unroll
                for (int r = 0; r < 4; ++r) {
                    const int m = (lane >> 4) * 4 + r;
                    const int c = lane & 15;
                    *(unsigned short*)(smem + h2_addr(m, 2 * ((2 * w + 0) * 16 + c))) = f2bf(h0[r] * h0[r]);
                    *(unsigned short*)(smem + h2_addr(m, 2 * ((2 * w + 1) * 16 + c))) = f2bf(h1[r] * h1[r]);
                }
            }
            __syncthreads();                 // b_B: h2 visible

            // ---- G: gamma = h2 @ W; 4 passes, wave owns nt {p*16+2w, +1} ----
            {
                f32x4 g0 = {0.f,0.f,0.f,0.f}, g1 = {0.f,0.f,0.f,0.f};
                bf16x8 bb[4][2];
                #pragma unroll
                for (int d = 0; d < 4; ++d) {   // batches u=0..3 (pass 0, kk=d)
                    bb[d][0] = pk[512 * 64 + (d * 64 + 0 * 16 + 2 * w + 0) * 64 + lane];
                    bb[d][1] = pk[512 * 64 + (d * 64 + 0 * 16 + 2 * w + 1) * 64 + lane];
                }
                #pragma unroll 4
                for (int u = 0; u < 32; ++u) {
                    const int kk = u & 7;        // K-subtile
                    const int pass = u >> 3;     // n-pass
                    const bf16x8 a = *(const bf16x8*)(smem + h2_addr(lane & 15, kk * 64 + (lane >> 4) * 16));
                    g0 = __builtin_amdgcn_mfma_f32_16x16x32_bf16(a, bb[u & 3][0], g0, 0, 0, 0);
                    g1 = __builtin_amdgcn_mfma_f32_16x16x32_bf16(a, bb[u & 3][1], g1, 0, 0, 0);
                    if (u + 4 < 32) {
                        const int u2 = u + 4;
                        const int kk2 = u2 & 7, p2 = u2 >> 3;
                        bb[u & 3][0] = pk[512 * 64 + (kk2 * 64 + p2 * 16 + 2 * w + 0) * 64 + lane];
                        bb[u & 3][1] = pk[512 * 64 + (kk2 * 64 + p2 * 16 + 2 * w + 1) * 64 + lane];
                    }
                    if (kk == 7) {               // end of pass: gamma -> dead vs cells
                        #pragma unroll
                        for (int r = 0; r < 4; ++r) {
                            const int m = (lane >> 4) * 4 + r;
                            const int c = lane & 15;
                            *(unsigned short*)(smem + vs_addr(m, 2 * ((pass * 16 + 2 * w + 0) * 16 + c))) = f2bf(g0[r]);
                            *(unsigned short*)(smem + vs_addr(m, 2 * ((pass * 16 + 2 * w + 1) * 16 + c))) = f2bf(g1[r]);
                        }
                        g0 = (f32x4){0.f,0.f,0.f,0.f};
                        g1 = (f32x4){0.f,0.f,0.f,0.f};
                    }
                }
            }
            __syncthreads();                 // b_C: gamma visible

            // ---- kick: gamma from vs cells, x from xsp; write v' to vs ----
            #pragma unroll
            for (int m = 0; m < NROWS; ++m) {
                const f32x2 fm = *(const f32x2*)&force[(row0 + m) * DIM + 2 * t];
                const f32x2 x2 = *(const f32x2*)&xsp[m * 1024 + 2 * t];
                const unsigned gu = *(const unsigned*)(smem + vs_addr(m, 4 * t));
                const float gL = bf2f((unsigned short)(gu & 0xFFFFu));
                const float gH = bf2f((unsigned short)(gu >> 16));
                const float sing = sings[m];
                unsigned pp = 0;
                #pragma unroll
                for (int j = 0; j < 2; ++j) {
                    const float g  = j ? gH : gL;
                    const float z  = x2[j] * vw[j];
                    const float e  = exp2f(z * 2.885390081777927f);   // e^(2z)
                    const float th = 1.f - 2.f / (e + 1.f);           // tanh(z)
                    const float gate = fmaf(0.1f, th, 1.f);
                    const float a = fm[j] - g * gate * sing;
                    vr[m][j] = fmaf(ddt, a, vr[m][j]);
                    pp |= ((unsigned)f2bf(vr[m][j])) << (16 * j);
                }
                *(unsigned*)(smem + vs_addr(m, 4 * t)) = pp;   // same-thread RMW
            }
            // next accel's b_A covers these vs writes
        } // sub

        // final drift: x += C5*dt*v  (LDS RMW, thread-private)
        const float c5dt = dt * (float)XI;
        #pragma unroll
        for (int m = 0; m < NROWS; ++m) {
            f32x2 x2 = *(f32x2*)&xsp[m * 1024 + 2 * t];
            x2[0] = fmaf(c5dt, vr[m][0], x2[0]);
            x2[1] = fmaf(c5dt, vr[m][1], x2[1]);
            *(f32x2*)&xsp[m * 1024 + 2 * t] = x2;
        }
    } // step

    __syncthreads();

    // ---- store (x, v) ----
    #pragma unroll
    for (int m = 0; m < NROWS; ++m) {
        const int base = (row0 + m) * DIM + 2 * t;
        const f32x2 x2 = *(const f32x2*)&xsp[m * 1024 + 2 * t];
        f32x2 vo; vo[0] = vr[m][0]; vo[1] = vr[m][1];
        *(f32x2*)&out[base] = x2;
        *(f32x2*)&out[OUT_HALF + base] = vo;
    }
}

extern "C" void kernel_launch(void* const* d_in, const int* in_sizes, int n_in,
                              void* d_out, int out_size, void* d_ws, size_t ws_size,
                              hipStream_t stream) {
    const float* x_in  = (const float*)d_in[0];
    const float* v_in  = (const float*)d_in[1];
    const float* force = (const float*)d_in[2];
    const float* Umat  = (const float*)d_in[3];
    const float* Wmat  = (const float*)d_in[4];
    const float* Vw    = (const float*)d_in[5];
    const int*   steps = (const int*)d_in[6];
    float* out = (float*)d_out;
    bf16x8* pk = (bf16x8*)d_ws;   // 1 MiB

    (void)hipFuncSetAttribute((const void*)omelyan_mfma,
                              hipFuncAttributeMaxDynamicSharedMemorySize,
                              SMEM_BYTES);

    prep_pack<<<dim3(256), dim3(256), 0, stream>>>(Umat, Wmat, pk);
    omelyan_mfma<<<dim3(TOTAL_ROWS / NROWS), dim3(NT), SMEM_BYTES, stream>>>(
        x_in, v_in, force, Vw, steps, pk, out);
}